// Round 13
// baseline (175.472 us; speedup 1.0000x reference)
//
#include <hip/hip_runtime.h>
#include <math.h>

static constexpr int B_  = 2;
static constexpr int S_  = 2048;
static constexpr int E_  = 1024;
static constexpr int NH_ = 4;
static constexpr int HD_ = 256;
static constexpr int BH_ = B_ * NH_;

typedef __attribute__((ext_vector_type(8))) _Float16 half8;
typedef __attribute__((ext_vector_type(4))) float    f32x4;
typedef __attribute__((ext_vector_type(4))) _Float16 half4v;

// ---------------- Kernel 1: prep v2 — gates (blocks 0..1023) | V-transpose (1024..2047) ----------------
// Gates: 4 rows/block, weights streamed from L2 (96 KB resident/XCD), float4
// input loads, coalesced half4 Q/K emission, 0.5 KB LDS -> many blocks/CU.
// Transpose: R3-validated 64x64 tile, 16.6 KB LDS.
__global__ __launch_bounds__(256) void prep_kernel(
    const float* __restrict__ q, const float* __restrict__ k, const float* __restrict__ v,
    const float* __restrict__ igk, const float* __restrict__ igb,
    const float* __restrict__ fgk, const float* __restrict__ fgb,
    float* __restrict__ ig_out, float* __restrict__ fg_out,
    _Float16* __restrict__ Qh, _Float16* __restrict__ Kh, _Float16* __restrict__ Vt)
{
    __shared__ __align__(16) char PSM[16640];
    const int tid = threadIdx.x;

    if (blockIdx.x < 1024) {
        // ---------------- gates: rows bs0..bs0+3 ----------------
        const int bs0 = blockIdx.x * 4;
        const float4* w_i = (const float4*)igk;   // row e = float4 of 4 heads
        const float4* w_f = (const float4*)fgk;

        float accI[4][4], accF[4][4];             // [row][head]
        #pragma unroll
        for (int r = 0; r < 4; ++r)
            #pragma unroll
            for (int h = 0; h < 4; ++h) { accI[r][h] = 0.f; accF[r][h] = 0.f; }

        #pragma unroll
        for (int it = 0; it < 3; ++it) {          // it: 0=q, 1=k, 2=v segment
            const int e4  = tid + 256 * it;       // float4 index in [0,768)
            const int e4l = e4 & 255;             // float4 index within segment
            const float* src = (it == 0) ? q : (it == 1) ? k : v;

            float4 g4[4];
            #pragma unroll
            for (int r = 0; r < 4; ++r)
                g4[r] = ((const float4*)(src + (size_t)(bs0 + r) * E_))[e4l];

            // fp16 emission for q (scaled 1/16) and k
            if (it == 0) {
                #pragma unroll
                for (int r = 0; r < 4; ++r) {
                    const int bs = bs0 + r, b = bs >> 11, s = bs & (S_ - 1);
                    half4v hq = { (_Float16)(g4[r].x * 0.0625f), (_Float16)(g4[r].y * 0.0625f),
                                  (_Float16)(g4[r].z * 0.0625f), (_Float16)(g4[r].w * 0.0625f) };
                    *(half4v*)(Qh + ((size_t)(b * NH_ + (e4l >> 6)) * S_ + s) * HD_ + (e4l & 63) * 4) = hq;
                }
            } else if (it == 1) {
                #pragma unroll
                for (int r = 0; r < 4; ++r) {
                    const int bs = bs0 + r, b = bs >> 11, s = bs & (S_ - 1);
                    half4v hk = { (_Float16)g4[r].x, (_Float16)g4[r].y,
                                  (_Float16)g4[r].z, (_Float16)g4[r].w };
                    *(half4v*)(Kh + ((size_t)(b * NH_ + (e4l >> 6)) * S_ + s) * HD_ + (e4l & 63) * 4) = hk;
                }
            }

            float4 wi4[4], wf4[4];
            #pragma unroll
            for (int j = 0; j < 4; ++j) {
                wi4[j] = w_i[e4 * 4 + j];
                wf4[j] = w_f[e4 * 4 + j];
            }
            #pragma unroll
            for (int r = 0; r < 4; ++r) {
                const float gx[4] = { g4[r].x, g4[r].y, g4[r].z, g4[r].w };
                #pragma unroll
                for (int j = 0; j < 4; ++j) {
                    accI[r][0] = fmaf(gx[j], wi4[j].x, accI[r][0]);
                    accI[r][1] = fmaf(gx[j], wi4[j].y, accI[r][1]);
                    accI[r][2] = fmaf(gx[j], wi4[j].z, accI[r][2]);
                    accI[r][3] = fmaf(gx[j], wi4[j].w, accI[r][3]);
                    accF[r][0] = fmaf(gx[j], wf4[j].x, accF[r][0]);
                    accF[r][1] = fmaf(gx[j], wf4[j].y, accF[r][1]);
                    accF[r][2] = fmaf(gx[j], wf4[j].z, accF[r][2]);
                    accF[r][3] = fmaf(gx[j], wf4[j].w, accF[r][3]);
                }
            }
        }
        // wave reduce (64 lanes) then cross-wave via LDS
        #pragma unroll
        for (int m = 1; m < 64; m <<= 1) {
            #pragma unroll
            for (int r = 0; r < 4; ++r)
                #pragma unroll
                for (int h = 0; h < 4; ++h) {
                    accI[r][h] += __shfl_xor(accI[r][h], m);
                    accF[r][h] += __shfl_xor(accF[r][h], m);
                }
        }
        float (*red)[4][8] = (float(*)[4][8])PSM;   // [wave][row][gate*4+head]
        const int wave = tid >> 6;
        if ((tid & 63) == 0) {
            #pragma unroll
            for (int r = 0; r < 4; ++r)
                #pragma unroll
                for (int h = 0; h < 4; ++h) {
                    red[wave][r][h]     = accI[r][h];
                    red[wave][r][4 + h] = accF[r][h];
                }
        }
        __syncthreads();
        if (tid < 32) {
            const int r = tid >> 3, c = tid & 7, h = c & 3;
            float sum = red[0][r][c] + red[1][r][c] + red[2][r][c] + red[3][r][c];
            const int bs = bs0 + r, b = bs >> 11, s = bs & (S_ - 1);
            if (c < 4) ig_out[((size_t)(b * NH_ + h)) * S_ + s] = sum + igb[h];
            else       fg_out[((size_t)(b * NH_ + h)) * S_ + s] = sum + fgb[h];
        }
    } else {
        // ---------------- V transpose: tile m ----------------
        float (*tile)[65] = (float(*)[65])PSM;
        const int m  = blockIdx.x - 1024;        // 0..1023
        const int bh = m & 7;
        const int sb = (m >> 3) & 31;
        const int db = m >> 8;                   // 0..3
        const int bb = bh >> 2, hh = bh & 3;
        const int j4 = (tid & 15) * 4;
        const int i0 = tid >> 4;
        const float* src = v + ((size_t)(bb * S_ + sb * 64)) * E_ + hh * HD_ + db * 64;
        #pragma unroll
        for (int p = 0; p < 4; ++p) {
            int i = i0 + p * 16;
            float4 val = *(const float4*)(src + (size_t)i * E_ + j4);
            tile[i][j4] = val.x; tile[i][j4+1] = val.y; tile[i][j4+2] = val.z; tile[i][j4+3] = val.w;
        }
        __syncthreads();
        const int s4 = (tid & 15) * 4;
        const int d0 = tid >> 4;
        _Float16* dst = Vt + ((size_t)bh * HD_ + db * 64) * S_ + sb * 64;
        #pragma unroll
        for (int p = 0; p < 4; ++p) {
            int d = d0 + p * 16;
            half4v pk;
            pk.x = (_Float16)tile[s4][d];   pk.y = (_Float16)tile[s4+1][d];
            pk.z = (_Float16)tile[s4+2][d]; pk.w = (_Float16)tile[s4+3][d];
            *(half4v*)(dst + (size_t)d * S_ + s4) = pk;
        }
    }
}

// ---------------- Kernel 2: 8-wave mlstm (unchanged R12, 68 us validated) ----------------
static constexpr int KSS = 264;   // Ks row stride (halfs)
static constexpr int VSS = 72;    // Vs row stride (halfs)
static constexpr int PBS = 72;    // P buf row stride (halfs)
static constexpr int OFF_VS  = 64 * KSS * 2;            // 33792
static constexpr int OFF_PB  = OFF_VS + 256 * VSS * 2;  // 70656
static constexpr int OFF_RSE = OFF_PB + 2 * 16 * PBS * 2; // 75264
static constexpr int OFF_SSE = OFF_RSE + 512;           // 75776
static constexpr int OFF_AMM = OFF_SSE + 512;           // 76288
static constexpr int OFF_G   = OFF_AMM + S_ * 4;        // 84480
static constexpr int OFF_M   = OFF_G   + S_ * 4;        // 92672
static constexpr int SMB     = OFF_M   + S_ * 4;        // 100864

__global__ __launch_bounds__(512, 2) void mlstm_kernel(
    const _Float16* __restrict__ Qh, const _Float16* __restrict__ Kh,
    const _Float16* __restrict__ Vt,
    const float* __restrict__ ig, const float* __restrict__ fg,
    const float* __restrict__ rms_scale, float* __restrict__ out)
{
    __shared__ __align__(16) char SMEM[SMB];
    _Float16* Ks    = (_Float16*)SMEM;                   // [64][KSS]
    _Float16* Vs    = (_Float16*)(SMEM + OFF_VS);        // [256][VSS]
    _Float16* Pb    = (_Float16*)(SMEM + OFF_PB);        // [2][16][PBS]
    float*    rsumE = (float*)(SMEM + OFF_RSE);          // [2][4][16]
    float*    ssE   = (float*)(SMEM + OFF_SSE);          // [2][4][16]
    float*    sAmM  = (float*)(SMEM + OFF_AMM);          // [S]
    float*    sG    = (float*)(SMEM + OFF_G);            // [S]
    float*    sM    = (float*)(SMEM + OFF_M);            // [S]

    const int z  = blockIdx.x;
    const int bh = z & 7;                 // one head per XCD
    const int u  = z >> 3;                // 0..31
    const int b  = bh >> 2, h = bh & 3;
    const int t  = threadIdx.x;
    const int w  = t >> 6;                // 0..7
    const int l  = t & 63;
    const int col  = l & 15;
    const int quad = l >> 4;
    const int qo   = quad * 8;
    const int rw   = w >> 2;              // row half (16 rows)
    const int cq   = w & 3;               // col quarter (16 of 64 cols)

    // ---- scan prologue: head-local AmM/G/M into LDS ----
    {
        float* sc = (float*)SMEM;         // 2 KB, aliased in Ks region
        const float* fgp = fg + (size_t)bh * S_;
        const float* igp = ig + (size_t)bh * S_;
        float ls[4];
        float run = 0.f;
        #pragma unroll
        for (int i = 0; i < 4; ++i) {
            float x = fgp[t * 4 + i];
            float lg = (x >= 0.f) ? -log1pf(expf(-x)) : (x - log1pf(expf(x)));
            run += lg;
            ls[i] = run;
        }
        sc[t] = run;
        __syncthreads();
        for (int off = 1; off < 512; off <<= 1) {
            float vv = (t >= off) ? sc[t - off] : 0.f;
            __syncthreads();
            sc[t] += vv;
            __syncthreads();
        }
        float excl = sc[t] - run;
        float A[4], g[4], gm[4];
        #pragma unroll
        for (int i = 0; i < 4; ++i) A[i] = excl + ls[i];
        float rmax = -__builtin_inff();
        #pragma unroll
        for (int i = 0; i < 4; ++i) {
            g[i] = igp[t * 4 + i] - A[i];
            rmax = fmaxf(rmax, g[i]);
            gm[i] = rmax;
        }
        __syncthreads();
        sc[t] = rmax;
        __syncthreads();
        for (int off = 1; off < 512; off <<= 1) {
            float vv = (t >= off) ? sc[t - off] : -__builtin_inff();
            __syncthreads();
            sc[t] = fmaxf(sc[t], vv);
            __syncthreads();
        }
        float exm = (t == 0) ? -__builtin_inff() : sc[t - 1];
        #pragma unroll
        for (int i = 0; i < 4; ++i) {
            float cm = fmaxf(exm, gm[i]);
            float Mi = A[i] + cm;
            sAmM[t * 4 + i] = A[i] - Mi;
            sG[t * 4 + i]   = g[i];
            sM[t * 4 + i]   = Mi;
        }
        __syncthreads();   // sAmM/sG/sM visible; sc alias retired
    }

    const _Float16* Qp  = Qh + (size_t)bh * S_ * HD_;
    const _Float16* Kp  = Kh + (size_t)bh * S_ * HD_;
    const _Float16* Vtp = Vt + (size_t)bh * HD_ * S_;
    _Float16* Pbr = Pb + rw * 16 * PBS;

    half8 kpre[4], vpre[4];
    auto issueK = [&](int c0n) {
        #pragma unroll
        for (int i = 0; i < 4; ++i) {
            int p = t + 512 * i;
            int row = p >> 5, ck = p & 31;
            kpre[i] = *(const half8*)(Kp + (size_t)(c0n + row) * HD_ + ck * 8);
        }
    };
    auto issueV = [&](int c0n) {
        #pragma unroll
        for (int i = 0; i < 4; ++i) {
            int p = t + 512 * i;
            int n = p >> 3, ch = p & 7;
            vpre[i] = *(const half8*)(Vtp + (size_t)n * S_ + c0n + ch * 8);
        }
    };

    issueK(0);
    issueV(0);

    for (int pass = 0; pass < 2; ++pass) {
        const int rb = pass ? (63 - u) : u;
        const int rowbase = rb * 32 + rw * 16;

        half8 qf[8];
        #pragma unroll
        for (int kk = 0; kk < 8; ++kk)
            qf[kk] = *(const half8*)(Qp + (size_t)(rowbase + col) * HD_ + kk * 32 + qo);
        float amM[4];
        #pragma unroll
        for (int rr = 0; rr < 4; ++rr) amM[rr] = sAmM[rowbase + quad * 4 + rr];

        f32x4 acc[4];
        #pragma unroll
        for (int nn = 0; nn < 4; ++nn) acc[nn] = (f32x4){0.f, 0.f, 0.f, 0.f};
        float rs[4] = {0.f, 0.f, 0.f, 0.f};

        const int Tt = (rb >> 1) + 1;
        for (int jt = 0; jt < Tt; ++jt) {
            const int c0 = jt << 6;
            __syncthreads();              // prior-iter Ks/Vs/Pb reads done
            #pragma unroll
            for (int i = 0; i < 4; ++i) { // drain K prefetch (vmcnt wait here)
                int p = t + 512 * i;
                int row = p >> 5, ck = p & 31;
                *(half8*)(Ks + row * KSS + ck * 8) = kpre[i];
            }
            #pragma unroll
            for (int i = 0; i < 4; ++i) { // drain V prefetch
                int p = t + 512 * i;
                int n = p >> 3, ch = p & 7;
                *(half8*)(Vs + n * VSS + ch * 8) = vpre[i];
            }
            __syncthreads();
            if (!(pass == 1 && jt + 1 == Tt)) {
                const int cn = (jt + 1 < Tt) ? (c0 + 64) : 0;
                issueK(cn);
                issueV(cn);
            }
            // ---- QK^T: this wave's 16 rows x 16 cols (quarter cq) ----
            const float gv = sG[c0 + cq * 16 + col];
            f32x4 sc0 = (f32x4){0.f,0.f,0.f,0.f};
            #pragma unroll
            for (int kk = 0; kk < 8; ++kk) {
                half8 kf = *(const half8*)(Ks + (cq * 16 + col) * KSS + kk * 32 + qo);
                sc0 = __builtin_amdgcn_mfma_f32_16x16x32_f16(qf[kk], kf, sc0, 0, 0, 0);
            }
            // ---- fixup: p = s * exp(AmM[i]+G[j]) (one exp!), mask by select ----
            #pragma unroll
            for (int rr = 0; rr < 4; ++rr) {
                const int ig_ = rowbase + quad * 4 + rr;
                float e0 = __expf(amM[rr] + gv);
                float p0 = (c0 + cq * 16 + col <= ig_) ? sc0[rr] * e0 : 0.f;
                rs[rr] += p0;
                Pbr[(quad * 4 + rr) * PBS + cq * 16 + col] = (_Float16)p0;
            }
            __syncthreads();              // publish P (cross-wave within row-half)
            // ---- PV n-split: A = P[rw](16x64), B = Vs n-slice, k = 64 ----
            half8 af0 = *(const half8*)(Pbr + col * PBS + qo);
            half8 af1 = *(const half8*)(Pbr + col * PBS + 32 + qo);
            #pragma unroll
            for (int nn = 0; nn < 4; ++nn) {
                const int n = cq * 64 + nn * 16 + col;
                half8 vf0 = *(const half8*)(Vs + n * VSS + qo);
                half8 vf1 = *(const half8*)(Vs + n * VSS + 32 + qo);
                acc[nn] = __builtin_amdgcn_mfma_f32_16x16x32_f16(af0, vf0, acc[nn], 0, 0, 0);
                acc[nn] = __builtin_amdgcn_mfma_f32_16x16x32_f16(af1, vf1, acc[nn], 0, 0, 0);
            }
        }

        // ---- epilogue: rowsum across quarters, normalize, RMSNorm, store slice ----
        #pragma unroll
        for (int m = 1; m < 16; m <<= 1) {
            #pragma unroll
            for (int rr = 0; rr < 4; ++rr) rs[rr] += __shfl_xor(rs[rr], m);
        }
        if (col == 0) {
            #pragma unroll
            for (int rr = 0; rr < 4; ++rr)
                rsumE[rw * 64 + cq * 16 + quad * 4 + rr] = rs[rr];
        }
        __syncthreads();
        float inv[4], ss[4];
        #pragma unroll
        for (int rr = 0; rr < 4; ++rr) {
            const int r = quad * 4 + rr;
            float tot = rsumE[rw * 64 + r] + rsumE[rw * 64 + 16 + r]
                      + rsumE[rw * 64 + 32 + r] + rsumE[rw * 64 + 48 + r];
            float Mv = sM[rowbase + r];
            float n = fmaxf(tot, __expf(-Mv)) + 1e-6f;
            inv[rr] = 1.0f / n;
            ss[rr] = 0.f;
        }
        #pragma unroll
        for (int nn = 0; nn < 4; ++nn) {
            #pragma unroll
            for (int rr = 0; rr < 4; ++rr) {
                float hv = acc[nn][rr] * inv[rr];
                acc[nn][rr] = hv;
                ss[rr] = fmaf(hv, hv, ss[rr]);
            }
        }
        #pragma unroll
        for (int m = 1; m < 16; m <<= 1) {
            #pragma unroll
            for (int rr = 0; rr < 4; ++rr) ss[rr] += __shfl_xor(ss[rr], m);
        }
        if (col == 0) {
            #pragma unroll
            for (int rr = 0; rr < 4; ++rr)
                ssE[rw * 64 + cq * 16 + quad * 4 + rr] = ss[rr];
        }
        __syncthreads();
        #pragma unroll
        for (int rr = 0; rr < 4; ++rr) {
            const int r = quad * 4 + rr;
            float sst = ssE[rw * 64 + r] + ssE[rw * 64 + 16 + r]
                      + ssE[rw * 64 + 32 + r] + ssE[rw * 64 + 48 + r];
            float rstd = rsqrtf(sst * (1.0f / HD_) + 1e-6f);
            float* orow = out + ((size_t)(b * S_ + rowbase + r)) * E_ + h * HD_;
            #pragma unroll
            for (int nn = 0; nn < 4; ++nn) {
                const int c = cq * 64 + nn * 16 + col;
                orow[c] = acc[nn][rr] * rstd * (1.0f + rms_scale[c]);
            }
        }
        __syncthreads();   // epilogue done before next pass reuses rsumE/ssE/Ks/Vs
    }
}

extern "C" void kernel_launch(void* const* d_in, const int* in_sizes, int n_in,
                              void* d_out, int out_size, void* d_ws, size_t ws_size,
                              hipStream_t stream) {
    (void)in_sizes; (void)n_in; (void)out_size; (void)ws_size;
    const float* q   = (const float*)d_in[0];
    const float* k   = (const float*)d_in[1];
    const float* v   = (const float*)d_in[2];
    const float* igk = (const float*)d_in[3];
    const float* igb = (const float*)d_in[4];
    const float* fgk = (const float*)d_in[5];
    const float* fgb = (const float*)d_in[6];
    const float* rsc = (const float*)d_in[7];
    float* out = (float*)d_out;

    float* ws  = (float*)d_ws;
    float* ig  = ws;                          // BH*S each
    float* fg  = ws + (size_t)BH_ * S_;
    _Float16* Qh = (_Float16*)(ws + (size_t)2 * BH_ * S_);
    _Float16* Kh = Qh + (size_t)BH_ * S_ * HD_;
    _Float16* Vt = Kh + (size_t)BH_ * S_ * HD_;

    prep_kernel<<<2048, 256, 0, stream>>>(q, k, v, igk, igb, fgk, fgb,
                                          ig, fg, Qh, Kh, Vt);
    mlstm_kernel<<<BH_ * 32, 512, 0, stream>>>(Qh, Kh, Vt, ig, fg, rsc, out);
}